// Round 1
// 1205.863 us; speedup vs baseline: 1.2626x; 1.2626x over previous
//
#include <hip/hip_runtime.h>
#include <math.h>

#define NTOT 32000000   // 4*128*250*250

typedef __attribute__((ext_vector_type(8))) short bf8_t;   // 8 bf16 (4 VGPRs)
typedef __attribute__((ext_vector_type(4))) float f4_t;    // MFMA accumulator

__device__ __forceinline__ float fast_tanh(float t) {
    return 1.0f - 2.0f / (1.0f + __expf(2.0f * t));
}
__device__ __forceinline__ float gelu_f(float v) {
    return 0.5f * v * (1.0f + fast_tanh(0.7978845608028654f * (v + 0.044715f * v * v * v)));
}
__device__ __forceinline__ float sigmoid_f(float v) {
    return 1.0f / (1.0f + __expf(-v));
}
__device__ __forceinline__ unsigned short f2bf(float f) {
    unsigned u = __float_as_uint(f);
    u = (u + 0x7FFFu + ((u >> 16) & 1u)) >> 16;
    return (unsigned short)u;
}
__device__ __forceinline__ float bf2f(unsigned short u) {
    return __uint_as_float(((unsigned)u) << 16);
}

// ---------- S4D discretization: store dt*Re(A), dt*Im(A), 2*C' ----------
__global__ void wc_kernel(const float* __restrict__ log_dt, const float* __restrict__ logA_re,
                          const float* __restrict__ A_im, const float* __restrict__ C_re,
                          const float* __restrict__ C_im, float* __restrict__ wC) {
    int t = blockIdx.x * 256 + threadIdx.x;
    if (t >= 128 * 32) return;
    int h = t >> 5, m = t & 31;
    float dt  = expf(log_dt[h]);
    float are = -expf(logA_re[t]);
    float aim = A_im[t];
    float er  = expf(dt * are);
    float wr  = er * cosf(dt * aim);
    float wi  = er * sinf(dt * aim);
    float e1r = wr - 1.0f, e1i = wi;
    float inv = 1.0f / (are * are + aim * aim);
    float qr  = (e1r * are + e1i * aim) * inv;
    float qi  = (e1i * are - e1r * aim) * inv;
    float cre = C_re[t], cim = C_im[t];
    wC[h * 128 + m]      = dt * are;                       // Re(dtA)
    wC[h * 128 + 32 + m] = dt * aim;                       // Im(dtA)
    wC[h * 128 + 64 + m] = 2.0f * (cre * qr - cim * qi);   // 2*Re(C')
    wC[h * 128 + 96 + m] = 2.0f * (cre * qi + cim * qr);   // 2*Im(C')
}

// ---------- materialize conv kernel: kern[h][l] = 2*Re(sum_m C'_m exp(dtA_m*l)) ----------
__global__ void kern_kernel(const float* __restrict__ wC, float* __restrict__ kern) {
    int h = blockIdx.x, l = threadIdx.x;   // 256 threads, valid l<250 (pad 0)
    const float* wc = wC + (h << 7);
    float acc = 0.0f;
    if (l < 250) {
        float fl = (float)l;
#pragma unroll 1
        for (int m = 0; m < 32; ++m) {
            float er  = expf(wc[m] * fl);
            float ang = wc[32 + m] * fl;
            float sv, cv;
            sincosf(ang, &sv, &cv);
            acc += er * (wc[64 + m] * cv - wc[96 + m] * sv);
        }
    }
    kern[(h << 8) + l] = acc;
}

// ---------- weight fp32 -> bf16 ----------
__global__ void cvtw_kernel(const float* __restrict__ ow, const float* __restrict__ lw,
                            unsigned short* __restrict__ owbf, unsigned short* __restrict__ lwbf) {
    int t = blockIdx.x * 256 + threadIdx.x;
    if (t < 32768) owbf[t] = f2bf(ow[t]);
    else if (t < 49152) lwbf[t - 32768] = f2bf(lw[t - 32768]);
}

// ---------- causal S4D conv as Toeplitz MFMA GEMM (bf16x3 ~ fp32), + D*u, GELU -> bf16 Y ----------
// Y layout [seq][h][l(250)] bf16, unchanged.
// intra: u[k][s] = in[b,h,k,s]: time=k (stride 250), seq=s (contig). seq=b*250+s, l=k.
// inter: u[s][?] : time=s (contig), seq=k.  seq=b*250+k, l=s.
// block: 256 l_out x 128 seq per (s-tile, h, b). 4 waves; wave w owns rows rt*64+w*16 (rt=0..3).
__global__ __launch_bounds__(256, 2)
void conv_kernel(const float* __restrict__ in, unsigned short* __restrict__ Y,
                 const float* __restrict__ kern, const float* __restrict__ Dv, int inter) {
    __shared__ unsigned short Bhi[128 * 264];   // [seq][k 0..255] hi bf16, pitch 264 (16B-aligned rows)
    __shared__ unsigned short Blo[128 * 40];    // [seq][k-chunk 0..31] lo bf16, pitch 40
    __shared__ float klds[512];                 // zero-pad [0..255], kern [256..511]
    const int tid = threadIdx.x;
    const int lane = tid & 63, wave = tid >> 6;
    const int lid = lane & 15, quad = lane >> 4;
    const int s0 = blockIdx.x * 128;
    const int h = blockIdx.y, b = blockIdx.z;
    klds[tid] = 0.0f;
    klds[256 + tid] = kern[(h << 8) + tid];
    const float Dh = Dv[h];
    const float* src = in + (long)(b * 128 + h) * 62500;

    f4_t acc[4][8];
#pragma unroll
    for (int rt = 0; rt < 4; ++rt)
#pragma unroll
        for (int ct = 0; ct < 8; ++ct) acc[rt][ct] = (f4_t)0.0f;

    float2 pf[8];
    auto loadc = [&](int c) {
        if (!inter) {
#pragma unroll
            for (int it = 0; it < 8; ++it) {
                int kk = (tid >> 6) + (it << 2);          // 0..31
                int k = (c << 5) + kk;
                int ss = (tid & 63) << 1;                 // 0..126
                bool v = (k < 250) && (s0 + ss < 250);
                pf[it] = v ? *(const float2*)(src + (long)k * 250 + s0 + ss)
                           : make_float2(0.0f, 0.0f);
            }
        } else {
#pragma unroll
            for (int it = 0; it < 8; ++it) {
                int kk2 = (tid >> 4) + (it << 4);         // seq 0..127
                int cc = (tid & 15) << 1;                 // 0..30
                bool v = (s0 + kk2 < 250) && ((c << 5) + cc < 250);
                pf[it] = v ? *(const float2*)(src + (long)(s0 + kk2) * 250 + (c << 5) + cc)
                           : make_float2(0.0f, 0.0f);
            }
        }
    };
    auto storec = [&](int c) {
        if (!inter) {
#pragma unroll
            for (int it = 0; it < 8; ++it) {
                int kk = (tid >> 6) + (it << 2);
                int k = (c << 5) + kk;
                int ss = (tid & 63) << 1;
                unsigned short hx = f2bf(pf[it].x);
                unsigned short hy = f2bf(pf[it].y);
                Bhi[ss * 264 + k] = hx;
                Bhi[(ss + 1) * 264 + k] = hy;
                Blo[ss * 40 + kk] = f2bf(pf[it].x - bf2f(hx));
                Blo[(ss + 1) * 40 + kk] = f2bf(pf[it].y - bf2f(hy));
            }
        } else {
#pragma unroll
            for (int it = 0; it < 8; ++it) {
                int kk2 = (tid >> 4) + (it << 4);
                int cc = (tid & 15) << 1;
                int k = (c << 5) + cc;
                unsigned short hx = f2bf(pf[it].x);
                unsigned short hy = f2bf(pf[it].y);
                Bhi[kk2 * 264 + k] = hx;
                Bhi[kk2 * 264 + k + 1] = hy;
                Blo[kk2 * 40 + cc] = f2bf(pf[it].x - bf2f(hx));
                Blo[kk2 * 40 + cc + 1] = f2bf(pf[it].y - bf2f(hy));
            }
        }
    };

    loadc(0);
#pragma unroll 1
    for (int c = 0; c < 8; ++c) {
        __syncthreads();           // prev compute done (Blo/Bhi-slice free)
        storec(c);
        __syncthreads();           // staging visible
        if (c < 7) loadc(c + 1);   // T14: issue next-chunk loads under the MFMAs
        const int c32 = c << 5;
        // build Toeplitz A-frags from kern (hi/lo), causality via zero padding
        bf8_t ah[4], al[4];
#pragma unroll
        for (int rt = 0; rt < 4; ++rt) {
            const int R = (rt << 6) + (wave << 4);
            if (c32 <= R + 15) {
                int d0 = 256 + R + lid - c32 - (quad << 3) - 7;
                float r[8];
#pragma unroll
                for (int j = 0; j < 8; ++j) r[j] = klds[d0 + j];
#pragma unroll
                for (int j = 0; j < 8; ++j) {
                    float v = r[7 - j];                   // A[R+lid][c32+8q+j] = kern[(R+lid)-(k)]
                    unsigned short hb = f2bf(v);
                    ah[rt][j] = (short)hb;
                    al[rt][j] = (short)f2bf(v - bf2f(hb));
                }
            }
        }
#pragma unroll
        for (int ct = 0; ct < 8; ++ct) {
            bf8_t bh = *(const bf8_t*)(Bhi + (ct * 16 + lid) * 264 + c32 + (quad << 3));
            bf8_t bl = *(const bf8_t*)(Blo + (ct * 16 + lid) * 40 + (quad << 3));
#pragma unroll
            for (int rt = 0; rt < 4; ++rt) {
                const int R = (rt << 6) + (wave << 4);
                if (c32 <= R + 15) {
                    acc[rt][ct] = __builtin_amdgcn_mfma_f32_16x16x32_bf16(ah[rt], bh, acc[rt][ct], 0, 0, 0);
                    acc[rt][ct] = __builtin_amdgcn_mfma_f32_16x16x32_bf16(ah[rt], bl, acc[rt][ct], 0, 0, 0);
                    acc[rt][ct] = __builtin_amdgcn_mfma_f32_16x16x32_bf16(al[rt], bh, acc[rt][ct], 0, 0, 0);
                }
            }
        }
    }
    __syncthreads();   // all MFMA reads of Bhi done before epilogue overwrites it
    // epilogue: y = acc + D*u, gelu, bf16; write back in-place into Bhi[seq][l]
#pragma unroll
    for (int rt = 0; rt < 4; ++rt) {
        const int Rq = (rt << 6) + (wave << 4) + (quad << 2);
#pragma unroll
        for (int ct = 0; ct < 8; ++ct) {
            const int sl = ct * 16 + lid;
#pragma unroll
            for (int reg = 0; reg < 4; ++reg) {
                int row = Rq + reg;
                float u = bf2f(Bhi[sl * 264 + row]);
                float y = acc[rt][ct][reg] + Dh * u;
                Bhi[sl * 264 + row] = f2bf(gelu_f(y));
            }
        }
    }
    __syncthreads();
    // coalesced copy-out: Y[(b*250+s0+sl)*128 + h][l], 250 bf16 = 125 u32 per row
    const unsigned int* Bu = (const unsigned int*)Bhi;   // u32 pitch 132
    unsigned int* Yg = (unsigned int*)Y + ((long)(b * 250 + s0) * 128 + h) * 125;
#pragma unroll 1
    for (int i = tid; i < 16384; i += 256) {
        int sl = i >> 7, e = i & 127;
        if (e < 125 && s0 + sl < 250)
            Yg[(long)sl * 16000 + e] = Bu[sl * 132 + e];
    }
}

// ---------- out-linear 128->256 (bf16 MFMA) + GLU -> bf16 G [seq][h][l(250)] ----------
// block: one seq, 64 l; 4 waves, wave w owns o-tiles {2w,2w+1,2w+8,2w+9} (GLU pairs in-wave)
__global__ __launch_bounds__(256)
void outlin_kernel(const unsigned short* __restrict__ Ybf, const unsigned short* __restrict__ owbf,
                   const float* __restrict__ ob, unsigned short* __restrict__ Gbf) {
    __shared__ unsigned short Yl[64 * 136];   // [l][h], pitch 136
    const int tid = threadIdx.x;
    const int lane = tid & 63, wave = tid >> 6;
    const int lid = lane & 15, quad = lane >> 4;
    const int l0g = blockIdx.x * 64;
    const int seq = blockIdx.y;
    const unsigned short* Ys = Ybf + (long)seq * 32000;
    // stage Y tile transposed: [h][l] -> LDS [l][h]
#pragma unroll 1
    for (int i = tid; i < 4096; i += 256) {
        int h = i >> 5, l2 = (i & 31) * 2;
        int l = l0g + l2;
        unsigned int v = 0;
        if (l < 250) v = *(const unsigned int*)(Ys + h * 250 + l);
        Yl[l2 * 136 + h] = (unsigned short)(v & 0xFFFF);
        Yl[(l2 + 1) * 136 + h] = (unsigned short)(v >> 16);
    }
    const int tb0 = 2 * wave;
    int tmap[4] = {tb0, tb0 + 1, tb0 + 8, tb0 + 9};
    bf8_t wf[4][4];   // [kchunk][tile]
#pragma unroll
    for (int c = 0; c < 4; ++c)
#pragma unroll
        for (int t = 0; t < 4; ++t)
            wf[c][t] = *(const bf8_t*)(owbf + (tmap[t] * 16 + lid) * 128 + c * 32 + quad * 8);
    __syncthreads();
    f4_t acc[4][4];   // [tile][ntile]
#pragma unroll
    for (int t = 0; t < 4; ++t)
#pragma unroll
        for (int j = 0; j < 4; ++j)
            acc[t][j] = (f4_t)0.0f;
#pragma unroll 1
    for (int c = 0; c < 4; ++c) {
        bf8_t bfr[4];
#pragma unroll
        for (int j = 0; j < 4; ++j)
            bfr[j] = *(const bf8_t*)(Yl + (j * 16 + lid) * 136 + c * 32 + quad * 8);
#pragma unroll
        for (int t = 0; t < 4; ++t)
#pragma unroll
            for (int j = 0; j < 4; ++j)
                acc[t][j] = __builtin_amdgcn_mfma_f32_16x16x32_bf16(wf[c][t], bfr[j], acc[t][j], 0, 0, 0);
    }
    // GLU epilogue: z1 = tiles tmap[0..1], z2 = tiles tmap[2..3] (= +128 channels)
#pragma unroll
    for (int p = 0; p < 2; ++p) {
        int ob0 = tmap[p] * 16 + quad * 4;
#pragma unroll
        for (int reg = 0; reg < 4; ++reg) {
            int o = ob0 + reg;
            float b1 = ob[o], b2 = ob[128 + o];
            unsigned short* Gr = Gbf + ((long)seq * 128 + o) * 250;
#pragma unroll
            for (int j = 0; j < 4; ++j) {
                int l = l0g + j * 16 + lid;
                if (l < 250) {
                    float z1 = acc[p][j][reg] + b1;
                    float z2 = acc[p + 2][j][reg] + b2;
                    Gr[l] = f2bf(z1 * sigmoid_f(z2));
                }
            }
        }
    }
}

// ---------- flat-view linear (bf16 MFMA): V[r][o] = G[r][c] @ lw^T + lb, r<250000 ----------
__global__ __launch_bounds__(256)
void viewlin_kernel(const unsigned short* __restrict__ Gbf, const unsigned short* __restrict__ lwbf,
                    const float* __restrict__ lb, float* __restrict__ V) {
    const int tid = threadIdx.x;
    const int lane = tid & 63, wave = tid >> 6;
    const int lid = lane & 15, quad = lane >> 4;
    const long r0 = (long)blockIdx.x * 128 + wave * 32;
    f4_t acc[2][8];
#pragma unroll
    for (int mt = 0; mt < 2; ++mt)
#pragma unroll
        for (int nt = 0; nt < 8; ++nt)
            acc[mt][nt] = (f4_t)0.0f;
#pragma unroll 1
    for (int c = 0; c < 4; ++c) {
        bf8_t af[2];
#pragma unroll
        for (int mt = 0; mt < 2; ++mt) {
            long r = r0 + mt * 16 + lid;
            if (r > 249999) r = 249999;
            af[mt] = *(const bf8_t*)(Gbf + r * 128 + c * 32 + quad * 8);
        }
#pragma unroll
        for (int nt = 0; nt < 8; ++nt) {
            bf8_t bfr = *(const bf8_t*)(lwbf + (nt * 16 + lid) * 128 + c * 32 + quad * 8);
            acc[0][nt] = __builtin_amdgcn_mfma_f32_16x16x32_bf16(af[0], bfr, acc[0][nt], 0, 0, 0);
            acc[1][nt] = __builtin_amdgcn_mfma_f32_16x16x32_bf16(af[1], bfr, acc[1][nt], 0, 0, 0);
        }
    }
#pragma unroll
    for (int nt = 0; nt < 8; ++nt) {
        int o = nt * 16 + lid;
        float bb = lb[o];
#pragma unroll
        for (int mt = 0; mt < 2; ++mt)
#pragma unroll
            for (int reg = 0; reg < 4; ++reg) {
                long r = r0 + mt * 16 + quad * 4 + reg;
                if (r < 250000) V[r * 128 + o] = acc[mt][nt][reg] + bb;
            }
    }
}

// ---------- GroupNorm stats ----------
__global__ void stats_kernel(const float* __restrict__ A, double* __restrict__ part) {
    __shared__ double ssum[256], ssq[256];
    const int blk = blockIdx.x;
    const int b = blk >> 8, sub = blk & 255;
    const long base = (long)b * 8000000 + (long)sub * 31250;
    double s = 0.0, q = 0.0;
    for (int i = threadIdx.x; i < 31250; i += 256) {
        float v = A[base + i];
        s += (double)v; q += (double)v * (double)v;
    }
    ssum[threadIdx.x] = s; ssq[threadIdx.x] = q;
    __syncthreads();
    for (int st = 128; st > 0; st >>= 1) {
        if (threadIdx.x < st) {
            ssum[threadIdx.x] += ssum[threadIdx.x + st];
            ssq[threadIdx.x]  += ssq[threadIdx.x + st];
        }
        __syncthreads();
    }
    if (threadIdx.x == 0) { part[blk * 2] = ssum[0]; part[blk * 2 + 1] = ssq[0]; }
}

__global__ void stats_final_kernel(const double* __restrict__ part, float* __restrict__ stats) {
    __shared__ double ssum[256], ssq[256];
    const int b = blockIdx.x;
    ssum[threadIdx.x] = part[(b * 256 + threadIdx.x) * 2];
    ssq[threadIdx.x]  = part[(b * 256 + threadIdx.x) * 2 + 1];
    __syncthreads();
    for (int st = 128; st > 0; st >>= 1) {
        if (threadIdx.x < st) {
            ssum[threadIdx.x] += ssum[threadIdx.x + st];
            ssq[threadIdx.x]  += ssq[threadIdx.x + st];
        }
        __syncthreads();
    }
    if (threadIdx.x == 0) {
        double mu = ssum[0] / 8000000.0;
        double var = ssq[0] / 8000000.0 - mu * mu;
        stats[b * 2] = (float)mu;
        stats[b * 2 + 1] = (float)(1.0 / sqrt(var + 1e-8));
    }
}

// ---------- intra finalize: transpose-back + GN affine + residual x -> out[B,N,K,S] ----------
__global__ void intra_fin_kernel(const float* __restrict__ f, const float* __restrict__ x,
                                 const float* __restrict__ stats, const float* __restrict__ gg,
                                 const float* __restrict__ gb, float* __restrict__ out) {
    __shared__ float tile[32][33];
    int kt = blockIdx.x, st = blockIdx.y;
    int bn = blockIdx.z; int b = bn >> 7, n = bn & 127;
    int tx = threadIdx.x & 31, ty = threadIdx.x >> 5;
    const float mu = stats[b * 2], rs = stats[b * 2 + 1];
    const float ga = gg[n] * rs, bb = gb[n];
    const float* fb = f + (long)(b * 250) * 32000 + n * 250;
#pragma unroll
    for (int j = 0; j < 4; ++j) {
        int k = kt * 32 + tx;
        int s = st * 32 + ty + j * 8;
        if (k < 250 && s < 250) tile[ty + j * 8][tx] = fb[(long)s * 32000 + k];
    }
    __syncthreads();
#pragma unroll
    for (int j = 0; j < 4; ++j) {
        int s = st * 32 + tx;
        int k = kt * 32 + ty + j * 8;
        if (k < 250 && s < 250) {
            long idx = ((long)(b * 128 + n) * 250 + k) * 250 + s;
            out[idx] = (tile[tx][ty + j * 8] - mu) * ga + bb + x[idx];
        }
    }
}

// ---------- final: out += GroupNorm(inter) transposed back ----------
__global__ void final_kernel(const float* __restrict__ f2, const float* __restrict__ stats,
                             const float* __restrict__ gg, const float* __restrict__ gb,
                             float* __restrict__ out) {
    long g = (long)blockIdx.x * 256 + threadIdx.x;
    if (g >= NTOT) return;
    int s = (int)(g % 250); long r = g / 250;
    int k = (int)(r % 250); long bn = r / 250;
    int n = (int)(bn % 128); int b = (int)(bn / 128);
    float mu = stats[b * 2], rs = stats[b * 2 + 1];
    float v = f2[((long)(b * 250 + k) * 128 + n) * 250 + s];
    out[g] = (v - mu) * rs * gg[n] + gb[n] + out[g];
}

extern "C" void kernel_launch(void* const* d_in, const int* in_sizes, int n_in,
                              void* d_out, int out_size, void* d_ws, size_t ws_size,
                              hipStream_t stream) {
    (void)in_sizes; (void)n_in; (void)out_size; (void)ws_size;
    const float* x = (const float*)d_in[0];
    float* out = (float*)d_out;
    char* base = (char*)d_ws;
    float* V            = (float*)base;                              // 128,000,000 B
    unsigned short* Ybf = (unsigned short*)(base + 128000000L);      //  64,000,000 B
    unsigned short* Gbf = (unsigned short*)(base + 192000000L);      //  64,000,000 B
    float* wC           = (float*)(base + 256000000L);               //      65,536 B
    unsigned short* owbf= (unsigned short*)(base + 256065536L);      //      65,536 B
    unsigned short* lwbf= (unsigned short*)(base + 256131072L);      //      32,768 B
    double* part        = (double*)(base + 256163840L);              //      16,384 B
    float* stats        = (float*)(base + 256180224L);               //          32 B
    // kern lives inside V's region (V is only written later by viewlin; conv reads kern first)
    float* kern         = (float*)(base + 120000000L);               //     131,072 B

    const float* i_logdt = (const float*)d_in[1];
    const float* i_logA  = (const float*)d_in[2];
    const float* i_Aim   = (const float*)d_in[3];
    const float* i_Cre   = (const float*)d_in[4];
    const float* i_Cim   = (const float*)d_in[5];
    const float* i_D     = (const float*)d_in[6];
    const float* i_ow    = (const float*)d_in[7];
    const float* i_ob    = (const float*)d_in[8];
    const float* i_lw    = (const float*)d_in[9];
    const float* i_lb    = (const float*)d_in[10];
    const float* i_gg    = (const float*)d_in[11];
    const float* i_gb    = (const float*)d_in[12];
    const float* e_logdt = (const float*)d_in[13];
    const float* e_logA  = (const float*)d_in[14];
    const float* e_Aim   = (const float*)d_in[15];
    const float* e_Cre   = (const float*)d_in[16];
    const float* e_Cim   = (const float*)d_in[17];
    const float* e_D     = (const float*)d_in[18];
    const float* e_ow    = (const float*)d_in[19];
    const float* e_ob    = (const float*)d_in[20];
    const float* e_lw    = (const float*)d_in[21];
    const float* e_lb    = (const float*)d_in[22];
    const float* e_gg    = (const float*)d_in[23];
    const float* e_gb    = (const float*)d_in[24];

    // ---- intra path ----
    wc_kernel<<<16, 256, 0, stream>>>(i_logdt, i_logA, i_Aim, i_Cre, i_Cim, wC);
    kern_kernel<<<128, 256, 0, stream>>>(wC, kern);
    cvtw_kernel<<<192, 256, 0, stream>>>(i_ow, i_lw, owbf, lwbf);
    conv_kernel<<<dim3(2, 128, 4), 256, 0, stream>>>(x, Ybf, kern, i_D, 0);
    outlin_kernel<<<dim3(4, 1000), 256, 0, stream>>>(Ybf, owbf, i_ob, Gbf);
    viewlin_kernel<<<1954, 256, 0, stream>>>(Gbf, lwbf, i_lb, V);
    stats_kernel<<<1024, 256, 0, stream>>>(V, part);
    stats_final_kernel<<<4, 256, 0, stream>>>(part, stats);
    intra_fin_kernel<<<dim3(8, 8, 512), 256, 0, stream>>>(V, x, stats, i_gg, i_gb, out);

    // ---- inter path ----
    wc_kernel<<<16, 256, 0, stream>>>(e_logdt, e_logA, e_Aim, e_Cre, e_Cim, wC);
    kern_kernel<<<128, 256, 0, stream>>>(wC, kern);
    cvtw_kernel<<<192, 256, 0, stream>>>(e_ow, e_lw, owbf, lwbf);
    conv_kernel<<<dim3(2, 128, 4), 256, 0, stream>>>(out, Ybf, kern, e_D, 1);
    outlin_kernel<<<dim3(4, 1000), 256, 0, stream>>>(Ybf, owbf, e_ob, Gbf);
    viewlin_kernel<<<1954, 256, 0, stream>>>(Gbf, lwbf, e_lb, V);
    stats_kernel<<<1024, 256, 0, stream>>>(V, part);
    stats_final_kernel<<<4, 256, 0, stream>>>(part, stats);
    final_kernel<<<NTOT / 256, 256, 0, stream>>>(V, stats, e_gg, e_gb, out);
}

// Round 2
// 811.370 us; speedup vs baseline: 1.8766x; 1.4862x over previous
//
#include <hip/hip_runtime.h>
#include <math.h>

#define NTOT 32000000   // 4*128*250*250

typedef __attribute__((ext_vector_type(8))) short bf8_t;   // 8 bf16 (4 VGPRs)
typedef __attribute__((ext_vector_type(4))) float f4_t;    // MFMA accumulator

__device__ __forceinline__ float fast_tanh(float t) {
    return 1.0f - 2.0f / (1.0f + __expf(2.0f * t));
}
__device__ __forceinline__ float gelu_f(float v) {
    return 0.5f * v * (1.0f + fast_tanh(0.7978845608028654f * (v + 0.044715f * v * v * v)));
}
__device__ __forceinline__ float sigmoid_f(float v) {
    return 1.0f / (1.0f + __expf(-v));
}
__device__ __forceinline__ unsigned short f2bf(float f) {
    unsigned u = __float_as_uint(f);
    u = (u + 0x7FFFu + ((u >> 16) & 1u)) >> 16;
    return (unsigned short)u;
}
__device__ __forceinline__ float bf2f(unsigned short u) {
    return __uint_as_float(((unsigned)u) << 16);
}
__device__ __forceinline__ unsigned swz(unsigned a) {   // flat-byte XOR swizzle
    return a ^ (((a >> 9) & 7u) << 4);
}

// ---------- S4D discretization: store dt*Re(A), dt*Im(A), 2*C' ----------
__global__ void wc_kernel(const float* __restrict__ log_dt, const float* __restrict__ logA_re,
                          const float* __restrict__ A_im, const float* __restrict__ C_re,
                          const float* __restrict__ C_im, float* __restrict__ wC) {
    int t = blockIdx.x * 256 + threadIdx.x;
    if (t >= 128 * 32) return;
    int h = t >> 5, m = t & 31;
    float dt  = expf(log_dt[h]);
    float are = -expf(logA_re[t]);
    float aim = A_im[t];
    float er  = expf(dt * are);
    float wr  = er * cosf(dt * aim);
    float wi  = er * sinf(dt * aim);
    float e1r = wr - 1.0f, e1i = wi;
    float inv = 1.0f / (are * are + aim * aim);
    float qr  = (e1r * are + e1i * aim) * inv;
    float qi  = (e1i * are - e1r * aim) * inv;
    float cre = C_re[t], cim = C_im[t];
    wC[h * 128 + m]      = dt * are;                       // Re(dtA)
    wC[h * 128 + 32 + m] = dt * aim;                       // Im(dtA)
    wC[h * 128 + 64 + m] = 2.0f * (cre * qr - cim * qi);   // 2*Re(C')
    wC[h * 128 + 96 + m] = 2.0f * (cre * qi + cim * qr);   // 2*Im(C')
}

// ---------- materialize conv kernel: kern[h][l] = 2*Re(sum_m C'_m exp(dtA_m*l)) ----------
__global__ void kern_kernel(const float* __restrict__ wC, float* __restrict__ kern) {
    int h = blockIdx.x, l = threadIdx.x;   // 256 threads, valid l<250 (pad 0)
    const float* wc = wC + (h << 7);
    float acc = 0.0f;
    if (l < 250) {
        float fl = (float)l;
#pragma unroll 1
        for (int m = 0; m < 32; ++m) {
            float er  = expf(wc[m] * fl);
            float ang = wc[32 + m] * fl;
            float sv, cv;
            sincosf(ang, &sv, &cv);
            acc += er * (wc[64 + m] * cv - wc[96 + m] * sv);
        }
    }
    kern[(h << 8) + l] = acc;
}

// ---------- weight fp32 -> bf16 ----------
__global__ void cvtw_kernel(const float* __restrict__ ow, const float* __restrict__ lw,
                            unsigned short* __restrict__ owbf, unsigned short* __restrict__ lwbf) {
    int t = blockIdx.x * 256 + threadIdx.x;
    if (t < 32768) owbf[t] = f2bf(ow[t]);
    else if (t < 49152) lwbf[t - 32768] = f2bf(lw[t - 32768]);
}

// ---------- causal S4D conv as Toeplitz MFMA GEMM (bf16x3 ~ fp32), + D*u, GELU -> bf16 Y ----------
__global__ __launch_bounds__(256, 2)
void conv_kernel(const float* __restrict__ in, unsigned short* __restrict__ Y,
                 const float* __restrict__ kern, const float* __restrict__ Dv, int inter) {
    __shared__ unsigned short Bhi[128 * 264];   // [seq][k 0..255] hi bf16, pitch 264
    __shared__ unsigned short Blo[128 * 40];    // [seq][k-chunk 0..31] lo bf16, pitch 40
    __shared__ float klds[512];                 // zero-pad [0..255], kern [256..511]
    const int tid = threadIdx.x;
    const int lane = tid & 63, wave = tid >> 6;
    const int lid = lane & 15, quad = lane >> 4;
    const int s0 = blockIdx.x * 128;
    const int h = blockIdx.y, b = blockIdx.z;
    klds[tid] = 0.0f;
    klds[256 + tid] = kern[(h << 8) + tid];
    const float Dh = Dv[h];
    const float* src = in + (long)(b * 128 + h) * 62500;

    f4_t acc[4][8];
#pragma unroll
    for (int rt = 0; rt < 4; ++rt)
#pragma unroll
        for (int ct = 0; ct < 8; ++ct) acc[rt][ct] = (f4_t)0.0f;

    float2 pf[8];
    auto loadc = [&](int c) {
        if (!inter) {
#pragma unroll
            for (int it = 0; it < 8; ++it) {
                int kk = (tid >> 6) + (it << 2);
                int k = (c << 5) + kk;
                int ss = (tid & 63) << 1;
                bool v = (k < 250) && (s0 + ss < 250);
                pf[it] = v ? *(const float2*)(src + (long)k * 250 + s0 + ss)
                           : make_float2(0.0f, 0.0f);
            }
        } else {
#pragma unroll
            for (int it = 0; it < 8; ++it) {
                int kk2 = (tid >> 4) + (it << 4);
                int cc = (tid & 15) << 1;
                bool v = (s0 + kk2 < 250) && ((c << 5) + cc < 250);
                pf[it] = v ? *(const float2*)(src + (long)(s0 + kk2) * 250 + (c << 5) + cc)
                           : make_float2(0.0f, 0.0f);
            }
        }
    };
    auto storec = [&](int c) {
        if (!inter) {
#pragma unroll
            for (int it = 0; it < 8; ++it) {
                int kk = (tid >> 6) + (it << 2);
                int k = (c << 5) + kk;
                int ss = (tid & 63) << 1;
                unsigned short hx = f2bf(pf[it].x);
                unsigned short hy = f2bf(pf[it].y);
                Bhi[ss * 264 + k] = hx;
                Bhi[(ss + 1) * 264 + k] = hy;
                Blo[ss * 40 + kk] = f2bf(pf[it].x - bf2f(hx));
                Blo[(ss + 1) * 40 + kk] = f2bf(pf[it].y - bf2f(hy));
            }
        } else {
#pragma unroll
            for (int it = 0; it < 8; ++it) {
                int kk2 = (tid >> 4) + (it << 4);
                int cc = (tid & 15) << 1;
                int k = (c << 5) + cc;
                unsigned short hx = f2bf(pf[it].x);
                unsigned short hy = f2bf(pf[it].y);
                Bhi[kk2 * 264 + k] = hx;
                Bhi[kk2 * 264 + k + 1] = hy;
                Blo[kk2 * 40 + cc] = f2bf(pf[it].x - bf2f(hx));
                Blo[kk2 * 40 + cc + 1] = f2bf(pf[it].y - bf2f(hy));
            }
        }
    };

    loadc(0);
#pragma unroll 1
    for (int c = 0; c < 8; ++c) {
        __syncthreads();
        storec(c);
        __syncthreads();
        if (c < 7) loadc(c + 1);
        const int c32 = c << 5;
        bf8_t ah[4], al[4];
#pragma unroll
        for (int rt = 0; rt < 4; ++rt) {
            const int R = (rt << 6) + (wave << 4);
            if (c32 <= R + 15) {
                int d0 = 256 + R + lid - c32 - (quad << 3) - 7;
                float r[8];
#pragma unroll
                for (int j = 0; j < 8; ++j) r[j] = klds[d0 + j];
#pragma unroll
                for (int j = 0; j < 8; ++j) {
                    float v = r[7 - j];
                    unsigned short hb = f2bf(v);
                    ah[rt][j] = (short)hb;
                    al[rt][j] = (short)f2bf(v - bf2f(hb));
                }
            }
        }
#pragma unroll
        for (int ct = 0; ct < 8; ++ct) {
            bf8_t bh = *(const bf8_t*)(Bhi + (ct * 16 + lid) * 264 + c32 + (quad << 3));
            bf8_t bl = *(const bf8_t*)(Blo + (ct * 16 + lid) * 40 + (quad << 3));
#pragma unroll
            for (int rt = 0; rt < 4; ++rt) {
                const int R = (rt << 6) + (wave << 4);
                if (c32 <= R + 15) {
                    acc[rt][ct] = __builtin_amdgcn_mfma_f32_16x16x32_bf16(ah[rt], bh, acc[rt][ct], 0, 0, 0);
                    acc[rt][ct] = __builtin_amdgcn_mfma_f32_16x16x32_bf16(ah[rt], bl, acc[rt][ct], 0, 0, 0);
                    acc[rt][ct] = __builtin_amdgcn_mfma_f32_16x16x32_bf16(al[rt], bh, acc[rt][ct], 0, 0, 0);
                }
            }
        }
    }
    __syncthreads();
#pragma unroll
    for (int rt = 0; rt < 4; ++rt) {
        const int Rq = (rt << 6) + (wave << 4) + (quad << 2);
#pragma unroll
        for (int ct = 0; ct < 8; ++ct) {
            const int sl = ct * 16 + lid;
#pragma unroll
            for (int reg = 0; reg < 4; ++reg) {
                int row = Rq + reg;
                float u = bf2f(Bhi[sl * 264 + row]);
                float y = acc[rt][ct][reg] + Dh * u;
                Bhi[sl * 264 + row] = f2bf(gelu_f(y));
            }
        }
    }
    __syncthreads();
    const unsigned int* Bu = (const unsigned int*)Bhi;   // u32 pitch 132
    unsigned int* Yg = (unsigned int*)Y + ((long)(b * 250 + s0) * 128 + h) * 125;
#pragma unroll 1
    for (int i = tid; i < 16384; i += 256) {
        int sl = i >> 7, e = i & 127;
        if (e < 125 && s0 + sl < 250)
            Yg[(long)sl * 16000 + e] = Bu[sl * 132 + e];
    }
}

// ---------- fused MLP: per-seq outlin(GEMM1)+GLU -> flat LDS -> viewlin(GEMM2) -> V + GN partials ----------
// block = one seq (1000 blocks), 4 waves.
// GEMM1: z[o][l] = ow[o][:]·Y[:, l], o<256, GLU pairs (o, o+128) -> G[h=o<128][l] bf16 in ZL (flat h*250+l, swizzled)
// GEMM2: V[r= seq*250+j][c] = flat(G)[j*128+:]·lw[c][:] + lb  (faithful .view semantics)
__global__ __launch_bounds__(256, 2)
void mlp_kernel(const unsigned short* __restrict__ Ybf, const unsigned short* __restrict__ owbf,
                const float* __restrict__ ob, const unsigned short* __restrict__ lwbf,
                const float* __restrict__ lb, float* __restrict__ V, double* __restrict__ part) {
    __shared__ unsigned short ZL[32768];     // 64 KiB: flat bf16 (h*250+l)*2 ^ swz
    __shared__ unsigned short Yt[32 * 136];  // chunk transpose [l(32)][h(128)] pitch 136
    const int tid = threadIdx.x;
    const int lane = tid & 63, wave = tid >> 6;
    const int lid = lane & 15, quad = lane >> 4;
    const int seq = blockIdx.x;
    const unsigned short* Ys = Ybf + (long)seq * 32000;

    // GEMM1 weights + biases (per wave: o-tiles {2w,2w+1,2w+8,2w+9})
    const int tb0 = 2 * wave;
    int tmap[4] = {tb0, tb0 + 1, tb0 + 8, tb0 + 9};
    bf8_t wf[4][4];
#pragma unroll
    for (int c = 0; c < 4; ++c)
#pragma unroll
        for (int t = 0; t < 4; ++t)
            wf[c][t] = *(const bf8_t*)(owbf + (tmap[t] * 16 + lid) * 128 + c * 32 + quad * 8);
    float ob1[2][4], ob2[2][4];
#pragma unroll
    for (int p = 0; p < 2; ++p)
#pragma unroll
        for (int reg = 0; reg < 4; ++reg) {
            int o = tmap[p] * 16 + quad * 4 + reg;
            ob1[p][reg] = ob[o];
            ob2[p][reg] = ob[128 + o];
        }

    unsigned int pf[8];
    auto loadc = [&](int l0) {
#pragma unroll
        for (int it = 0; it < 8; ++it) {
            int i = tid + it * 256;
            int h = i >> 4;
            int l = l0 + (i & 15) * 2;
            pf[it] = (l < 250) ? *(const unsigned int*)(Ys + h * 250 + l) : 0u;
        }
    };
    auto storec = [&]() {
#pragma unroll
        for (int it = 0; it < 8; ++it) {
            int i = tid + it * 256;
            int h = i >> 4;
            int l2 = (i & 15) * 2;
            Yt[l2 * 136 + h] = (unsigned short)(pf[it] & 0xFFFF);
            Yt[(l2 + 1) * 136 + h] = (unsigned short)(pf[it] >> 16);
        }
    };

    loadc(0);
#pragma unroll 1
    for (int ch = 0; ch < 8; ++ch) {
        __syncthreads();
        storec();
        __syncthreads();
        if (ch < 7) loadc((ch + 1) * 32);
        f4_t acc[4][2];
#pragma unroll
        for (int t = 0; t < 4; ++t)
#pragma unroll
            for (int jj = 0; jj < 2; ++jj) acc[t][jj] = (f4_t)0.0f;
#pragma unroll
        for (int c = 0; c < 4; ++c) {
            bf8_t bfr[2];
#pragma unroll
            for (int jj = 0; jj < 2; ++jj)
                bfr[jj] = *(const bf8_t*)(Yt + (jj * 16 + lid) * 136 + c * 32 + quad * 8);
#pragma unroll
            for (int t = 0; t < 4; ++t)
#pragma unroll
                for (int jj = 0; jj < 2; ++jj)
                    acc[t][jj] = __builtin_amdgcn_mfma_f32_16x16x32_bf16(wf[c][t], bfr[jj], acc[t][jj], 0, 0, 0);
        }
        const int lbase = ch * 32;
#pragma unroll
        for (int p = 0; p < 2; ++p) {
            int ob0 = tmap[p] * 16 + quad * 4;
#pragma unroll
            for (int reg = 0; reg < 4; ++reg) {
                int o = ob0 + reg;
#pragma unroll
                for (int jj = 0; jj < 2; ++jj) {
                    int l = lbase + jj * 16 + lid;
                    if (l < 250) {
                        float z1 = acc[p][jj][reg] + ob1[p][reg];
                        float z2 = acc[p + 2][jj][reg] + ob2[p][reg];
                        unsigned a = swz((unsigned)(o * 250 + l) * 2u);
                        *(unsigned short*)((char*)ZL + a) = f2bf(z1 * sigmoid_f(z2));
                    }
                }
            }
        }
    }
    __syncthreads();

    // GEMM2: 4 waves x 64 flat rows each
    f4_t acc2[4][8];
#pragma unroll
    for (int mt = 0; mt < 4; ++mt)
#pragma unroll
        for (int nt = 0; nt < 8; ++nt) acc2[mt][nt] = (f4_t)0.0f;
    const int j0 = wave * 64;
#pragma unroll
    for (int c = 0; c < 4; ++c) {
        bf8_t af[4];
#pragma unroll
        for (int mt = 0; mt < 4; ++mt) {
            unsigned a = swz((unsigned)((j0 + mt * 16 + lid) * 128 + c * 32 + quad * 8) * 2u);
            af[mt] = *(const bf8_t*)((char*)ZL + a);
        }
#pragma unroll
        for (int nt = 0; nt < 8; ++nt) {
            bf8_t bfr = *(const bf8_t*)(lwbf + (nt * 16 + lid) * 128 + c * 32 + quad * 8);
#pragma unroll
            for (int mt = 0; mt < 4; ++mt)
                acc2[mt][nt] = __builtin_amdgcn_mfma_f32_16x16x32_bf16(af[mt], bfr, acc2[mt][nt], 0, 0, 0);
        }
    }
    // store V + GroupNorm partial sums
    double s = 0.0, q = 0.0;
    float* Vs = V + (long)seq * 32000;
#pragma unroll
    for (int nt = 0; nt < 8; ++nt) {
        int o = nt * 16 + lid;
        float bb = lb[o];
#pragma unroll
        for (int mt = 0; mt < 4; ++mt)
#pragma unroll
            for (int reg = 0; reg < 4; ++reg) {
                int j = j0 + mt * 16 + quad * 4 + reg;
                if (j < 250) {
                    float v = acc2[mt][nt][reg] + bb;
                    Vs[j * 128 + o] = v;
                    s += (double)v;
                    q += (double)v * (double)v;
                }
            }
    }
    __syncthreads();
    double* red = (double*)Yt;   // 512 doubles = 4 KiB <= 8704 B
    red[tid] = s;
    red[256 + tid] = q;
    __syncthreads();
    for (int st = 128; st > 0; st >>= 1) {
        if (tid < st) {
            red[tid] += red[tid + st];
            red[256 + tid] += red[256 + tid + st];
        }
        __syncthreads();
    }
    if (tid == 0) {
        part[seq * 2] = red[0];
        part[seq * 2 + 1] = red[256];
    }
}

// ---------- reduce per-seq partials (250 per batch) -> mean, rstd ----------
__global__ void stats_final_kernel(const double* __restrict__ part, float* __restrict__ stats) {
    __shared__ double ssum[256], ssq[256];
    const int b = blockIdx.x;
    double s = 0.0, q = 0.0;
    if (threadIdx.x < 250) {
        s = part[(b * 250 + threadIdx.x) * 2];
        q = part[(b * 250 + threadIdx.x) * 2 + 1];
    }
    ssum[threadIdx.x] = s; ssq[threadIdx.x] = q;
    __syncthreads();
    for (int st = 128; st > 0; st >>= 1) {
        if (threadIdx.x < st) {
            ssum[threadIdx.x] += ssum[threadIdx.x + st];
            ssq[threadIdx.x]  += ssq[threadIdx.x + st];
        }
        __syncthreads();
    }
    if (threadIdx.x == 0) {
        double mu = ssum[0] / 8000000.0;
        double var = ssq[0] / 8000000.0 - mu * mu;
        stats[b * 2] = (float)mu;
        stats[b * 2 + 1] = (float)(1.0 / sqrt(var + 1e-8));
    }
}

// ---------- intra finalize: transpose-back + GN affine + residual x -> out[B,N,K,S] ----------
__global__ void intra_fin_kernel(const float* __restrict__ f, const float* __restrict__ x,
                                 const float* __restrict__ stats, const float* __restrict__ gg,
                                 const float* __restrict__ gb, float* __restrict__ out) {
    __shared__ float tile[32][33];
    int kt = blockIdx.x, st = blockIdx.y;
    int bn = blockIdx.z; int b = bn >> 7, n = bn & 127;
    int tx = threadIdx.x & 31, ty = threadIdx.x >> 5;
    const float mu = stats[b * 2], rs = stats[b * 2 + 1];
    const float ga = gg[n] * rs, bb = gb[n];
    const float* fb = f + (long)(b * 250) * 32000 + n * 250;
#pragma unroll
    for (int j = 0; j < 4; ++j) {
        int k = kt * 32 + tx;
        int s = st * 32 + ty + j * 8;
        if (k < 250 && s < 250) tile[ty + j * 8][tx] = fb[(long)s * 32000 + k];
    }
    __syncthreads();
#pragma unroll
    for (int j = 0; j < 4; ++j) {
        int s = st * 32 + tx;
        int k = kt * 32 + ty + j * 8;
        if (k < 250 && s < 250) {
            long idx = ((long)(b * 128 + n) * 250 + k) * 250 + s;
            out[idx] = (tile[tx][ty + j * 8] - mu) * ga + bb + x[idx];
        }
    }
}

// ---------- final: out += GroupNorm(inter) transposed back ----------
__global__ void final_kernel(const float* __restrict__ f2, const float* __restrict__ stats,
                             const float* __restrict__ gg, const float* __restrict__ gb,
                             float* __restrict__ out) {
    long g = (long)blockIdx.x * 256 + threadIdx.x;
    if (g >= NTOT) return;
    int s = (int)(g % 250); long r = g / 250;
    int k = (int)(r % 250); long bn = r / 250;
    int n = (int)(bn % 128); int b = (int)(bn / 128);
    float mu = stats[b * 2], rs = stats[b * 2 + 1];
    float v = f2[((long)(b * 250 + k) * 128 + n) * 250 + s];
    out[g] = (v - mu) * rs * gg[n] + gb[n] + out[g];
}

extern "C" void kernel_launch(void* const* d_in, const int* in_sizes, int n_in,
                              void* d_out, int out_size, void* d_ws, size_t ws_size,
                              hipStream_t stream) {
    (void)in_sizes; (void)n_in; (void)out_size; (void)ws_size;
    const float* x = (const float*)d_in[0];
    float* out = (float*)d_out;
    char* base = (char*)d_ws;
    float* V            = (float*)base;                              // 128,000,000 B
    unsigned short* Ybf = (unsigned short*)(base + 128000000L);      //  64,000,000 B
    float* wC           = (float*)(base + 256000000L);               //      65,536 B
    unsigned short* owbf= (unsigned short*)(base + 256065536L);      //      65,536 B
    unsigned short* lwbf= (unsigned short*)(base + 256131072L);      //      32,768 B
    double* part        = (double*)(base + 256163840L);              //      16,384 B
    float* stats        = (float*)(base + 256180224L);               //          32 B
    // kern lives inside V's region (V is only written later by mlp; conv reads kern first)
    float* kern         = (float*)(base + 120000000L);               //     131,072 B

    const float* i_logdt = (const float*)d_in[1];
    const float* i_logA  = (const float*)d_in[2];
    const float* i_Aim   = (const float*)d_in[3];
    const float* i_Cre   = (const float*)d_in[4];
    const float* i_Cim   = (const float*)d_in[5];
    const float* i_D     = (const float*)d_in[6];
    const float* i_ow    = (const float*)d_in[7];
    const float* i_ob    = (const float*)d_in[8];
    const float* i_lw    = (const float*)d_in[9];
    const float* i_lb    = (const float*)d_in[10];
    const float* i_gg    = (const float*)d_in[11];
    const float* i_gb    = (const float*)d_in[12];
    const float* e_logdt = (const float*)d_in[13];
    const float* e_logA  = (const float*)d_in[14];
    const float* e_Aim   = (const float*)d_in[15];
    const float* e_Cre   = (const float*)d_in[16];
    const float* e_Cim   = (const float*)d_in[17];
    const float* e_D     = (const float*)d_in[18];
    const float* e_ow    = (const float*)d_in[19];
    const float* e_ob    = (const float*)d_in[20];
    const float* e_lw    = (const float*)d_in[21];
    const float* e_lb    = (const float*)d_in[22];
    const float* e_gg    = (const float*)d_in[23];
    const float* e_gb    = (const float*)d_in[24];

    // ---- intra path ----
    wc_kernel<<<16, 256, 0, stream>>>(i_logdt, i_logA, i_Aim, i_Cre, i_Cim, wC);
    kern_kernel<<<128, 256, 0, stream>>>(wC, kern);
    cvtw_kernel<<<192, 256, 0, stream>>>(i_ow, i_lw, owbf, lwbf);
    conv_kernel<<<dim3(2, 128, 4), 256, 0, stream>>>(x, Ybf, kern, i_D, 0);
    mlp_kernel<<<1000, 256, 0, stream>>>(Ybf, owbf, i_ob, lwbf, i_lb, V, part);
    stats_final_kernel<<<4, 256, 0, stream>>>(part, stats);
    intra_fin_kernel<<<dim3(8, 8, 512), 256, 0, stream>>>(V, x, stats, i_gg, i_gb, out);

    // ---- inter path ----
    wc_kernel<<<16, 256, 0, stream>>>(e_logdt, e_logA, e_Aim, e_Cre, e_Cim, wC);
    kern_kernel<<<128, 256, 0, stream>>>(wC, kern);
    cvtw_kernel<<<192, 256, 0, stream>>>(e_ow, e_lw, owbf, lwbf);
    conv_kernel<<<dim3(2, 128, 4), 256, 0, stream>>>(out, Ybf, kern, e_D, 1);
    mlp_kernel<<<1000, 256, 0, stream>>>(Ybf, owbf, e_ob, lwbf, e_lb, V, part);
    stats_final_kernel<<<4, 256, 0, stream>>>(part, stats);
    final_kernel<<<NTOT / 256, 256, 0, stream>>>(V, stats, e_gg, e_gb, out);
}